// Round 6
// baseline (1606.574 us; speedup 1.0000x reference)
//
#include <hip/hip_runtime.h>
#include <hip/hip_bf16.h>

#define DD 128

typedef _Float16 h8_t __attribute__((ext_vector_type(8)));
typedef _Float16 h4_t __attribute__((ext_vector_type(4)));
typedef _Float16 h2_t __attribute__((ext_vector_type(2)));

__device__ inline float bf2f(unsigned short u) {
  union { unsigned int i; float f; } v;
  v.i = ((unsigned int)u) << 16;
  return v.f;
}

__device__ inline float sat(float v) {
  return fminf(fmaxf(v, -60000.f), 60000.f);
}

// dtype-adaptive scalar load: mode 1 = float32 array, mode 0 = bf16 array
__device__ inline float ldf(const void* p, int i, int f32m) {
  return f32m ? ((const float*)p)[i] : bf2f(((const unsigned short*)p)[i]);
}

// flag=1 -> f32 inputs (bf16-decoding f32 words' ushort halves gives wild
// exponents ~55% of the time; true-bf16 data gives ~0%).
__global__ __launch_bounds__(256) void k_detect(const unsigned int* __restrict__ nf,
                                                int* __restrict__ flag) {
  __shared__ int cnt;
  if (threadIdx.x == 0) cnt = 0;
  __syncthreads();
  int bad = 0;
#pragma unroll
  for (int k = 0; k < 8; ++k) {
    unsigned int w = nf[threadIdx.x * 8 + k];
#pragma unroll
    for (int h = 0; h < 2; ++h) {
      unsigned short us = (h == 0) ? (unsigned short)(w & 0xFFFF)
                                   : (unsigned short)(w >> 16);
      float v = bf2f(us);
      float av = fabsf(v);
      if (!(av <= 1e5f) || (av != 0.f && av < 1e-30f)) bad++;
    }
  }
  atomicAdd(&cnt, bad);
  __syncthreads();
  if (threadIdx.x == 0) *flag = (cnt > 200) ? 1 : 0;
}

// ---------------- CSR build ----------------

__global__ __launch_bounds__(256) void k_hist(const int* __restrict__ row,
                                              int* __restrict__ deg, int E, int N) {
  int i = blockIdx.x * 256 + threadIdx.x;
  if (i < E) {
    int r = row[i];
    if ((unsigned)r < (unsigned)N) atomicAdd(&deg[r], 1);
  }
}

__global__ __launch_bounds__(256) void k_scan_simple(const int* __restrict__ deg,
                                                     int* __restrict__ offs,
                                                     int* __restrict__ cursor,
                                                     int n, int chunk) {
  __shared__ int sh[257];
  int tid = threadIdx.x;
  int c0 = tid * chunk;
  int c1 = c0 + chunk;
  if (c0 > n) c0 = n;
  if (c1 > n) c1 = n;
  int s = 0;
  for (int i = c0; i < c1; ++i) s += deg[i];
  sh[tid] = s;
  __syncthreads();
  if (tid == 0) {
    int run = 0;
    for (int i = 0; i < 256; ++i) {
      int t = sh[i];
      sh[i] = run;
      run += t;
    }
    sh[256] = run;
  }
  __syncthreads();
  int run = sh[tid];
  for (int i = c0; i < c1; ++i) {
    offs[i] = run;
    cursor[i] = run;
    run += deg[i];
  }
  if (tid == 0) offs[n] = sh[256];
}

__global__ __launch_bounds__(256) void k_fill(const int* __restrict__ row,
                                              const int* __restrict__ col,
                                              const void* __restrict__ ew,
                                              int* __restrict__ cursor,
                                              int* __restrict__ ccol,
                                              _Float16* __restrict__ cw, int E, int N,
                                              const int* __restrict__ flag) {
  int f32m = *flag;
  int i = blockIdx.x * 256 + threadIdx.x;
  if (i >= E) return;
  int r = row[i];
  if ((unsigned)r >= (unsigned)N) return;
  int p = atomicAdd(&cursor[r], 1);
  if ((unsigned)p >= (unsigned)E) return;
  int c = col[i];
  if ((unsigned)c >= (unsigned)N) c = 0;
  ccol[p] = c;
  cw[p] = (_Float16)ldf(ew, i, f32m);
}

// ---------------- conversions ----------------

__global__ __launch_bounds__(256) void k_cvt_w(const void* __restrict__ W1,
                                               const void* __restrict__ W2,
                                               const void* __restrict__ W3,
                                               _Float16* __restrict__ Wt,
                                               const int* __restrict__ flag) {
  int f32m = *flag;
  int i = blockIdx.x * 256 + threadIdx.x;
  if (i >= 3 * 16384) return;
  int l = i >> 14, o = i & 16383;
  const void* W = (l == 0) ? W1 : (l == 1 ? W2 : W3);
  Wt[i] = (_Float16)ldf(W, o, f32m);
}

__global__ __launch_bounds__(256) void k_cvt_x(const void* __restrict__ in,
                                               h4_t* __restrict__ out, int n4,
                                               const int* __restrict__ flag) {
  int f32m = *flag;
  int i = blockIdx.x * 256 + threadIdx.x;
  if (i >= n4) return;
  h4_t o;
  if (f32m) {
    float4 v = ((const float4*)in)[i];
    o = h4_t{(_Float16)v.x, (_Float16)v.y, (_Float16)v.z, (_Float16)v.w};
  } else {
    ushort4 v = ((const ushort4*)in)[i];
    o = h4_t{(_Float16)bf2f(v.x), (_Float16)bf2f(v.y),
             (_Float16)bf2f(v.z), (_Float16)bf2f(v.w)};
  }
  out[i] = o;
}

// ---------------- GEMM (VALU): H = X @ W ----------------

__global__ __launch_bounds__(256) void k_gemm_valu(const _Float16* __restrict__ X,
                                                   const _Float16* __restrict__ W,
                                                   _Float16* __restrict__ H, int nrows) {
  int g = blockIdx.x * 256 + threadIdx.x;
  int r = g >> 5;
  if (r >= nrows) return;
  int f0 = (g & 31) << 2;
  const h8_t* xr = (const h8_t*)(X + (size_t)r * DD);
  float a0 = 0.f, a1 = 0.f, a2 = 0.f, a3 = 0.f;
#pragma unroll 4
  for (int kk = 0; kk < 16; ++kk) {
    h8_t xv = xr[kk];
#pragma unroll
    for (int j = 0; j < 8; ++j) {
      float xs = (float)xv[j];
      h4_t wv = *(const h4_t*)(W + ((kk * 8 + j) << 7) + f0);
      a0 = fmaf(xs, (float)wv[0], a0);
      a1 = fmaf(xs, (float)wv[1], a1);
      a2 = fmaf(xs, (float)wv[2], a2);
      a3 = fmaf(xs, (float)wv[3], a3);
    }
  }
  h4_t o = {(_Float16)sat(a0), (_Float16)sat(a1), (_Float16)sat(a2), (_Float16)sat(a3)};
  *(h4_t*)(H + (size_t)r * DD + f0) = o;
}

// ---------------- CSR aggregation ----------------
// FINAL=0: write fp16 pairs (internal activations). FINAL=1: write FLOAT32
// (d_out's true dtype — the reference's output is float32).

template <int FINAL>
__global__ __launch_bounds__(256) void k_agg(const _Float16* __restrict__ h,
                                             const int* __restrict__ offs,
                                             const int* __restrict__ ccol,
                                             const _Float16* __restrict__ cw,
                                             const void* __restrict__ bias,
                                             void* __restrict__ outp, int n, int E,
                                             const int* __restrict__ flag) {
  int f32m = *flag;
  int node = (blockIdx.x << 2) + (threadIdx.x >> 6);
  if (node >= n) return;
  int lane = threadIdx.x & 63;
  int beg = offs[node], end = offs[node + 1];
  if (beg < 0) beg = 0;
  if (end > E) end = E;
  const unsigned int* h32 = (const unsigned int*)h;
  float a0 = 0.f, a1 = 0.f;
  for (int base = beg; base < end; base += 64) {
    int mm = end - base;
    if (mm > 64) mm = 64;
    int c = 0;
    float w = 0.f;
    if (lane < mm) {
      c = ccol[base + lane];
      w = (float)cw[base + lane];
    }
    for (int j = 0; j < mm; ++j) {
      int cc = __shfl(c, j, 64);
      float ww = __shfl(w, j, 64);
      if ((unsigned)cc >= (unsigned)n) cc = 0;
      unsigned int pk = h32[(size_t)cc * 64 + lane];
      union { unsigned int u; _Float16 f[2]; } cv;
      cv.u = pk;
      a0 = fmaf((float)cv.f[0], ww, a0);
      a1 = fmaf((float)cv.f[1], ww, a1);
    }
  }
  int c0 = lane << 1;
  float o0 = sat(a0 + ldf(bias, c0, f32m)), o1 = sat(a1 + ldf(bias, c0 + 1, f32m));
  if (FINAL) {
    ((float2*)outp)[(size_t)node * 64 + lane] = make_float2(o0, o1);
  } else {
    h2_t v = {(_Float16)o0, (_Float16)o1};
    ((h2_t*)outp)[(size_t)node * 64 + lane] = v;
  }
}

// ---------------- BN stats ----------------

__global__ __launch_bounds__(256) void k_stats(const _Float16* __restrict__ x,
                                               float* __restrict__ gsum,
                                               float* __restrict__ gsumsq,
                                               int rpb, int n) {
  int c = threadIdx.x & 127, hh = threadIdx.x >> 7;
  int r0 = blockIdx.x * rpb;
  int r1 = r0 + rpb;
  if (r1 > n) r1 = n;
  float s = 0.f, s2 = 0.f;
  for (int r = r0 + hh; r < r1; r += 2) {
    float v = (float)x[(size_t)r * DD + c];
    s += v;
    s2 = fmaf(v, v, s2);
  }
  __shared__ float ls[256], ls2[256];
  ls[threadIdx.x] = s;
  ls2[threadIdx.x] = s2;
  __syncthreads();
  if (threadIdx.x < 128) {
    atomicAdd(&gsum[c], ls[c] + ls[c + 128]);
    atomicAdd(&gsumsq[c], ls2[c] + ls2[c + 128]);
  }
}

// ---------------- fused BN-apply + poly (in place, fp16) ----------------

__global__ __launch_bounds__(256) void k_polybn(_Float16* __restrict__ buf,
                                                const float* __restrict__ gsum,
                                                const float* __restrict__ gsumsq,
                                                const void* __restrict__ gamma,
                                                const void* __restrict__ beta,
                                                const void* __restrict__ coeffs,
                                                int coff,
                                                int total2, float invN,
                                                const int* __restrict__ flag) {
  int f32m = *flag;
  int i = blockIdx.x * 256 + threadIdx.x;
  if (i >= total2) return;
  int c0 = (i & 63) << 1;
  float p0 = ldf(coeffs, coff + 0, f32m), p1 = ldf(coeffs, coff + 1, f32m),
        p2 = ldf(coeffs, coff + 2, f32m), p3 = ldf(coeffs, coff + 3, f32m),
        p4 = ldf(coeffs, coff + 4, f32m);
  h2_t hv = ((const h2_t*)buf)[i];
  h2_t ov;
#pragma unroll
  for (int j = 0; j < 2; ++j) {
    int c = c0 + j;
    float v = (float)(j ? hv.y : hv.x);
    float mn = gsum[c] * invN;
    float var = fmaf(-mn, mn, gsumsq[c] * invN);
    var = fmaxf(var, 0.0f);
    float inv = rsqrtf(var + 1e-5f);
    float xn = (v - mn) * inv * ldf(gamma, c, f32m) + ldf(beta, c, f32m);
    xn = fminf(fmaxf(xn, -100.f), 100.f);  // never binds when stats match data
    float a = p4;
    a = fmaf(a, xn, p3);
    a = fmaf(a, xn, p2);
    a = fmaf(a, xn, p1);
    a = fmaf(a, xn, p0);
    a = sat(a);
    if (j) ov.y = (_Float16)a;
    else ov.x = (_Float16)a;
  }
  ((h2_t*)buf)[i] = ov;
}

// ---------------- launch ----------------

extern "C" void kernel_launch(void* const* d_in, const int* in_sizes, int n_in,
                              void* d_out, int out_size, void* d_ws, size_t ws_size,
                              hipStream_t stream) {
  const void* nf = d_in[0];
  const int* row = (const int*)d_in[1];
  const int* col = (const int*)d_in[2];
  const void* ew = d_in[3];
  const void* W1 = d_in[4];
  const void* b1 = d_in[5];
  const void* W2 = d_in[6];
  const void* b2 = d_in[7];
  const void* W3 = d_in[8];
  const void* b3 = d_in[9];
  const void* g1 = d_in[10];
  const void* be1 = d_in[11];
  const void* g2 = d_in[12];
  const void* be2 = d_in[13];
  const void* coeffs = d_in[14];

  const int N = in_sizes[0] / DD;
  const int E = in_sizes[1];
  const int cstride = in_sizes[14] / 2;  // coeffs is [2, order+1]

  // ws budget ~36.6MB (proven available: round5 took the CSR path).
  char* p = (char*)d_ws;
  auto alloc = [&](size_t bytes) {
    char* r = p;
    p += (bytes + 255) & ~(size_t)255;
    return r;
  };
  int* flag = (int*)alloc(256);
  float* stats = (float*)alloc(1024);
  float* gsum = stats;
  float* gsumsq = stats + 128;
  _Float16* Wt = (_Float16*)alloc(3 * 16384 * 2);
  _Float16* H16 = (_Float16*)alloc((size_t)N * DD * 2);
  int* deg = (int*)alloc((size_t)N * 4);
  int* offs = (int*)alloc((size_t)(N + 1) * 4);
  int* cursor = (int*)alloc((size_t)N * 4);
  int* ccol = (int*)alloc((size_t)E * 4);
  _Float16* cw = (_Float16*)alloc((size_t)E * 2);

  // fp16 activation scratch = first 25.6MB of d_out (d_out is 51.2MB of f32;
  // the final k_agg<1> overwrites all of it with float32 results).
  _Float16* OUT = (_Float16*)d_out;

  k_detect<<<1, 256, 0, stream>>>((const unsigned int*)nf, flag);

  int eb = (E + 255) / 256;
  hipMemsetAsync(deg, 0, (size_t)N * 4, stream);
  k_hist<<<eb, 256, 0, stream>>>(row, deg, E, N);
  int chunk = (N + 255) / 256;
  k_scan_simple<<<1, 256, 0, stream>>>(deg, offs, cursor, N, chunk);
  k_fill<<<eb, 256, 0, stream>>>(row, col, ew, cursor, ccol, cw, E, N, flag);

  k_cvt_w<<<192, 256, 0, stream>>>(W1, W2, W3, Wt, flag);
  k_cvt_x<<<((N * DD / 4) + 255) / 256, 256, 0, stream>>>(nf, (h4_t*)OUT,
                                                          N * DD / 4, flag);

  int gemm_blocks = ((N * 32) + 255) / 256;
  int agg_blocks = (N + 3) / 4;
  int rpb = (N + 399) / 400;
  float invN = 1.0f / (float)N;
  int total2 = N * 64;
  int pb = (total2 + 255) / 256;

  const void* Bs[3] = {b1, b2, b3};
  const void* Gs[2] = {g1, g2};
  const void* Bes[2] = {be1, be2};
  for (int l = 0; l < 3; ++l) {
    k_gemm_valu<<<gemm_blocks, 256, 0, stream>>>(OUT, Wt + l * 16384, H16, N);
    if (l < 2) {
      k_agg<0><<<agg_blocks, 256, 0, stream>>>(H16, offs, ccol, cw, Bs[l], OUT,
                                               N, E, flag);
      hipMemsetAsync(stats, 0, 1024, stream);
      k_stats<<<400, 256, 0, stream>>>(OUT, gsum, gsumsq, rpb, N);
      k_polybn<<<pb, 256, 0, stream>>>(OUT, gsum, gsumsq, Gs[l], Bes[l],
                                       coeffs, l * cstride, total2, invN, flag);
    } else {
      k_agg<1><<<agg_blocks, 256, 0, stream>>>(H16, offs, ccol, cw, Bs[l], d_out,
                                               N, E, flag);
    }
  }
}

// Round 7
// 843.183 us; speedup vs baseline: 1.9054x; 1.9054x over previous
//
#include <hip/hip_runtime.h>
#include <hip/hip_bf16.h>

#define DD 128

typedef _Float16 h8_t __attribute__((ext_vector_type(8)));
typedef _Float16 h4_t __attribute__((ext_vector_type(4)));
typedef _Float16 h2_t __attribute__((ext_vector_type(2)));
typedef float f4_t __attribute__((ext_vector_type(4)));

__device__ inline float bf2f(unsigned short u) {
  union { unsigned int i; float f; } v;
  v.i = ((unsigned int)u) << 16;
  return v.f;
}

__device__ inline float sat(float v) {
  return fminf(fmaxf(v, -60000.f), 60000.f);
}

// dtype-adaptive scalar load: mode 1 = float32 array, mode 0 = bf16 array
__device__ inline float ldf(const void* p, int i, int f32m) {
  return f32m ? ((const float*)p)[i] : bf2f(((const unsigned short*)p)[i]);
}

// flag=1 -> f32 inputs
__global__ __launch_bounds__(256) void k_detect(const unsigned int* __restrict__ nf,
                                                int* __restrict__ flag) {
  __shared__ int cnt;
  if (threadIdx.x == 0) cnt = 0;
  __syncthreads();
  int bad = 0;
#pragma unroll
  for (int k = 0; k < 8; ++k) {
    unsigned int w = nf[threadIdx.x * 8 + k];
#pragma unroll
    for (int h = 0; h < 2; ++h) {
      unsigned short us = (h == 0) ? (unsigned short)(w & 0xFFFF)
                                   : (unsigned short)(w >> 16);
      float v = bf2f(us);
      float av = fabsf(v);
      if (!(av <= 1e5f) || (av != 0.f && av < 1e-30f)) bad++;
    }
  }
  atomicAdd(&cnt, bad);
  __syncthreads();
  if (threadIdx.x == 0) *flag = (cnt > 200) ? 1 : 0;
}

// ---------------- CSR build ----------------

__global__ __launch_bounds__(256) void k_hist(const int* __restrict__ row,
                                              int* __restrict__ deg, int E, int N) {
  int i = blockIdx.x * 256 + threadIdx.x;
  if (i < E) {
    int r = row[i];
    if ((unsigned)r < (unsigned)N) atomicAdd(&deg[r], 1);
  }
}

// parallel scan, 3 passes, 1024 elems/block
__global__ __launch_bounds__(256) void k_scan1(const int* __restrict__ deg,
                                               int* __restrict__ bsum, int n) {
  int i0 = blockIdx.x * 1024 + threadIdx.x * 4;
  int s = 0;
#pragma unroll
  for (int k = 0; k < 4; ++k) {
    int i = i0 + k;
    if (i < n) s += deg[i];
  }
#pragma unroll
  for (int d = 1; d < 64; d <<= 1) s += __shfl_xor(s, d, 64);
  __shared__ int ws[4];
  int lane = threadIdx.x & 63, w = threadIdx.x >> 6;
  if (lane == 0) ws[w] = s;
  __syncthreads();
  if (threadIdx.x == 0) bsum[blockIdx.x] = ws[0] + ws[1] + ws[2] + ws[3];
}

// exclusive scan of nb block sums (nb <= 1024); also writes offs[n] = total
__global__ __launch_bounds__(1024) void k_scan2(int* __restrict__ bsum,
                                                int* __restrict__ offs,
                                                int nb, int n) {
  __shared__ int sh[1024];
  int tid = threadIdx.x;
  sh[tid] = (tid < nb) ? bsum[tid] : 0;
  __syncthreads();
  if (tid == 0) {
    int run = 0;
    for (int i = 0; i < nb; ++i) {
      int t = sh[i];
      sh[i] = run;
      run += t;
    }
    offs[n] = run;
  }
  __syncthreads();
  if (tid < nb) bsum[tid] = sh[tid];
}

__global__ __launch_bounds__(256) void k_scan3(const int* __restrict__ deg,
                                               const int* __restrict__ bsum,
                                               int* __restrict__ offs,
                                               int* __restrict__ cursor, int n) {
  int tid = threadIdx.x, lane = tid & 63, w = tid >> 6;
  int i0 = blockIdx.x * 1024 + tid * 4;
  int v0 = 0, v1 = 0, v2 = 0, v3 = 0;
  if (i0 + 3 < n) {
    v0 = deg[i0]; v1 = deg[i0 + 1]; v2 = deg[i0 + 2]; v3 = deg[i0 + 3];
  } else {
    if (i0 < n) v0 = deg[i0];
    if (i0 + 1 < n) v1 = deg[i0 + 1];
    if (i0 + 2 < n) v2 = deg[i0 + 2];
  }
  int s = v0 + v1 + v2 + v3;
  int sc = s;
#pragma unroll
  for (int d = 1; d < 64; d <<= 1) {
    int t = __shfl_up(sc, d, 64);
    if (lane >= d) sc += t;
  }
  __shared__ int ws[4];
  if (lane == 63) ws[w] = sc;
  __syncthreads();
  int wbase = 0;
  for (int x = 0; x < w; ++x) wbase += ws[x];
  int run = bsum[blockIdx.x] + wbase + (sc - s);
  if (i0 < n)     { offs[i0] = run;     cursor[i0] = run;     run += v0; }
  if (i0 + 1 < n) { offs[i0 + 1] = run; cursor[i0 + 1] = run; run += v1; }
  if (i0 + 2 < n) { offs[i0 + 2] = run; cursor[i0 + 2] = run; run += v2; }
  if (i0 + 3 < n) { offs[i0 + 3] = run; cursor[i0 + 3] = run; }
}

__global__ __launch_bounds__(256) void k_fill(const int* __restrict__ row,
                                              const int* __restrict__ col,
                                              const void* __restrict__ ew,
                                              int* __restrict__ cursor,
                                              int* __restrict__ ccol,
                                              _Float16* __restrict__ cw, int E, int N,
                                              const int* __restrict__ flag) {
  int f32m = *flag;
  int i = blockIdx.x * 256 + threadIdx.x;
  if (i >= E) return;
  int r = row[i];
  if ((unsigned)r >= (unsigned)N) return;
  int p = atomicAdd(&cursor[r], 1);
  if ((unsigned)p >= (unsigned)E) return;
  int c = col[i];
  if ((unsigned)c >= (unsigned)N) c = 0;
  ccol[p] = c;
  cw[p] = (_Float16)ldf(ew, i, f32m);
}

// ---------------- conversions ----------------

// W [128x128] -> fp16 in MFMA-B-fragment-swizzled order:
// Wt[l][((t*4+kk)*64+lane)*8+j] = W_l[kk*32 + (lane>>4)*8 + j][t*16 + (lane&15)]
__global__ __launch_bounds__(256) void k_cvt_w(const void* __restrict__ W1,
                                               const void* __restrict__ W2,
                                               const void* __restrict__ W3,
                                               _Float16* __restrict__ Wt,
                                               const int* __restrict__ flag) {
  int f32m = *flag;
  int i = blockIdx.x * 256 + threadIdx.x;
  if (i >= 3 * 16384) return;
  int l = i >> 14, o = i & 16383;
  int j = o & 7, lane = (o >> 3) & 63, kkt = o >> 9;
  int kk = kkt & 3, t = kkt >> 2;
  int k = kk * 32 + (lane >> 4) * 8 + j;
  int n = t * 16 + (lane & 15);
  const void* W = (l == 0) ? W1 : (l == 1 ? W2 : W3);
  Wt[i] = (_Float16)ldf(W, k * 128 + n, f32m);
}

__global__ __launch_bounds__(256) void k_cvt_x(const void* __restrict__ in,
                                               h4_t* __restrict__ out, int n4,
                                               const int* __restrict__ flag) {
  int f32m = *flag;
  int i = blockIdx.x * 256 + threadIdx.x;
  if (i >= n4) return;
  h4_t o;
  if (f32m) {
    float4 v = ((const float4*)in)[i];
    o = h4_t{(_Float16)v.x, (_Float16)v.y, (_Float16)v.z, (_Float16)v.w};
  } else {
    ushort4 v = ((const ushort4*)in)[i];
    o = h4_t{(_Float16)bf2f(v.x), (_Float16)bf2f(v.y),
             (_Float16)bf2f(v.z), (_Float16)bf2f(v.w)};
  }
  out[i] = o;
}

// ---------------- GEMM (MFMA): H = X @ W ----------------
// one wave per 16 rows; 8 col-tiles x 4 k-steps of mfma_f32_16x16x32_f16.
// A frag: m=lane&15, k=(lane>>4)*8+j.  B frag (pre-swizzled Wt): contiguous
// 16B per lane.  C/D: col=lane&15, row=(lane>>4)*4+reg.

__global__ __launch_bounds__(256) void k_gemm(const _Float16* __restrict__ X,
                                              const _Float16* __restrict__ Wt,
                                              _Float16* __restrict__ H, int nrows) {
  int gw = (blockIdx.x * 256 + threadIdx.x) >> 6;
  int lane = threadIdx.x & 63;
  int r0 = gw << 4;
  if (r0 >= nrows) return;
  int m = lane & 15, q = lane >> 4;
  int rr = r0 + m;
  if (rr >= nrows) rr = nrows - 1;
  f4_t acc[8] = {};
  const h8_t* Xf = (const h8_t*)(X + (size_t)rr * DD + q * 8);
#pragma unroll
  for (int kk = 0; kk < 4; ++kk) {
    h8_t a = Xf[kk * 4];
#pragma unroll
    for (int t = 0; t < 8; ++t) {
      h8_t b = *(const h8_t*)(Wt + (((t * 4 + kk) * 64 + lane) << 3));
      acc[t] = __builtin_amdgcn_mfma_f32_16x16x32_f16(a, b, acc[t], 0, 0, 0);
    }
  }
#pragma unroll
  for (int t = 0; t < 8; ++t) {
#pragma unroll
    for (int r = 0; r < 4; ++r) {
      int orow = r0 + q * 4 + r;
      if (orow < nrows)
        H[(size_t)orow * DD + t * 16 + m] = (_Float16)sat(acc[t][r]);
    }
  }
}

// ---------------- CSR aggregation ----------------
// FINAL=0: fp16 internal.  FINAL=1: float32 (d_out's real dtype).

template <int FINAL>
__global__ __launch_bounds__(256) void k_agg(const _Float16* __restrict__ h,
                                             const int* __restrict__ offs,
                                             const int* __restrict__ ccol,
                                             const _Float16* __restrict__ cw,
                                             const void* __restrict__ bias,
                                             void* __restrict__ outp, int n, int E,
                                             const int* __restrict__ flag) {
  int f32m = *flag;
  int node = (blockIdx.x << 2) + (threadIdx.x >> 6);
  if (node >= n) return;
  int lane = threadIdx.x & 63;
  int beg = offs[node], end = offs[node + 1];
  if (beg < 0) beg = 0;
  if (end > E) end = E;
  const unsigned int* h32 = (const unsigned int*)h;
  float a0 = 0.f, a1 = 0.f;
  for (int base = beg; base < end; base += 64) {
    int mm = end - base;
    if (mm > 64) mm = 64;
    int c = 0;
    float w = 0.f;
    if (lane < mm) {
      c = ccol[base + lane];
      w = (float)cw[base + lane];
    }
    for (int j = 0; j < mm; ++j) {
      int cc = __shfl(c, j, 64);
      float ww = __shfl(w, j, 64);
      if ((unsigned)cc >= (unsigned)n) cc = 0;
      unsigned int pk = h32[(size_t)cc * 64 + lane];
      union { unsigned int u; _Float16 f[2]; } cv;
      cv.u = pk;
      a0 = fmaf((float)cv.f[0], ww, a0);
      a1 = fmaf((float)cv.f[1], ww, a1);
    }
  }
  int c0 = lane << 1;
  float o0 = sat(a0 + ldf(bias, c0, f32m)), o1 = sat(a1 + ldf(bias, c0 + 1, f32m));
  if (FINAL) {
    ((float2*)outp)[(size_t)node * 64 + lane] = make_float2(o0, o1);
  } else {
    h2_t v = {(_Float16)o0, (_Float16)o1};
    ((h2_t*)outp)[(size_t)node * 64 + lane] = v;
  }
}

// ---------------- BN stats ----------------

__global__ __launch_bounds__(256) void k_stats(const _Float16* __restrict__ x,
                                               float* __restrict__ gsum,
                                               float* __restrict__ gsumsq,
                                               int rpb, int n) {
  int c = threadIdx.x & 127, hh = threadIdx.x >> 7;
  int r0 = blockIdx.x * rpb;
  int r1 = r0 + rpb;
  if (r1 > n) r1 = n;
  float s = 0.f, s2 = 0.f;
  for (int r = r0 + hh; r < r1; r += 2) {
    float v = (float)x[(size_t)r * DD + c];
    s += v;
    s2 = fmaf(v, v, s2);
  }
  __shared__ float ls[256], ls2[256];
  ls[threadIdx.x] = s;
  ls2[threadIdx.x] = s2;
  __syncthreads();
  if (threadIdx.x < 128) {
    atomicAdd(&gsum[c], ls[c] + ls[c + 128]);
    atomicAdd(&gsumsq[c], ls2[c] + ls2[c + 128]);
  }
}

// ---------------- fused BN-apply + poly (in place, fp16) ----------------

__global__ __launch_bounds__(256) void k_polybn(_Float16* __restrict__ buf,
                                                const float* __restrict__ gsum,
                                                const float* __restrict__ gsumsq,
                                                const void* __restrict__ gamma,
                                                const void* __restrict__ beta,
                                                const void* __restrict__ coeffs,
                                                int coff,
                                                int total2, float invN,
                                                const int* __restrict__ flag) {
  int f32m = *flag;
  int i = blockIdx.x * 256 + threadIdx.x;
  if (i >= total2) return;
  int c0 = (i & 63) << 1;
  float p0 = ldf(coeffs, coff + 0, f32m), p1 = ldf(coeffs, coff + 1, f32m),
        p2 = ldf(coeffs, coff + 2, f32m), p3 = ldf(coeffs, coff + 3, f32m),
        p4 = ldf(coeffs, coff + 4, f32m);
  h2_t hv = ((const h2_t*)buf)[i];
  h2_t ov;
#pragma unroll
  for (int j = 0; j < 2; ++j) {
    int c = c0 + j;
    float v = (float)(j ? hv.y : hv.x);
    float mn = gsum[c] * invN;
    float var = fmaf(-mn, mn, gsumsq[c] * invN);
    var = fmaxf(var, 0.0f);
    float inv = rsqrtf(var + 1e-5f);
    float xn = (v - mn) * inv * ldf(gamma, c, f32m) + ldf(beta, c, f32m);
    xn = fminf(fmaxf(xn, -100.f), 100.f);
    float a = p4;
    a = fmaf(a, xn, p3);
    a = fmaf(a, xn, p2);
    a = fmaf(a, xn, p1);
    a = fmaf(a, xn, p0);
    a = sat(a);
    if (j) ov.y = (_Float16)a;
    else ov.x = (_Float16)a;
  }
  ((h2_t*)buf)[i] = ov;
}

// ---------------- launch ----------------

extern "C" void kernel_launch(void* const* d_in, const int* in_sizes, int n_in,
                              void* d_out, int out_size, void* d_ws, size_t ws_size,
                              hipStream_t stream) {
  const void* nf = d_in[0];
  const int* row = (const int*)d_in[1];
  const int* col = (const int*)d_in[2];
  const void* ew = d_in[3];
  const void* W1 = d_in[4];
  const void* b1 = d_in[5];
  const void* W2 = d_in[6];
  const void* b2 = d_in[7];
  const void* W3 = d_in[8];
  const void* b3 = d_in[9];
  const void* g1 = d_in[10];
  const void* be1 = d_in[11];
  const void* g2 = d_in[12];
  const void* be2 = d_in[13];
  const void* coeffs = d_in[14];

  const int N = in_sizes[0] / DD;
  const int E = in_sizes[1];
  const int cstride = in_sizes[14] / 2;

  char* p = (char*)d_ws;
  auto alloc = [&](size_t bytes) {
    char* r = p;
    p += (bytes + 255) & ~(size_t)255;
    return r;
  };
  int* flag = (int*)alloc(256);
  float* stats = (float*)alloc(1024);
  float* gsum = stats;
  float* gsumsq = stats + 128;
  int* bsum = (int*)alloc(4096);  // up to 1024 scan blocks
  _Float16* Wt = (_Float16*)alloc(3 * 16384 * 2);
  _Float16* H16 = (_Float16*)alloc((size_t)N * DD * 2);
  int* deg = (int*)alloc((size_t)N * 4);
  int* offs = (int*)alloc((size_t)(N + 1) * 4);
  int* cursor = (int*)alloc((size_t)N * 4);
  int* ccol = (int*)alloc((size_t)E * 4);
  _Float16* cw = (_Float16*)alloc((size_t)E * 2);

  _Float16* OUT = (_Float16*)d_out;  // fp16 scratch; k_agg<1> rewrites as f32

  k_detect<<<1, 256, 0, stream>>>((const unsigned int*)nf, flag);

  int eb = (E + 255) / 256;
  hipMemsetAsync(deg, 0, (size_t)N * 4, stream);
  k_hist<<<eb, 256, 0, stream>>>(row, deg, E, N);
  int nb = (N + 1023) / 1024;
  k_scan1<<<nb, 256, 0, stream>>>(deg, bsum, N);
  k_scan2<<<1, 1024, 0, stream>>>(bsum, offs, nb, N);
  k_scan3<<<nb, 256, 0, stream>>>(deg, bsum, offs, cursor, N);
  k_fill<<<eb, 256, 0, stream>>>(row, col, ew, cursor, ccol, cw, E, N, flag);

  k_cvt_w<<<192, 256, 0, stream>>>(W1, W2, W3, Wt, flag);
  k_cvt_x<<<((N * DD / 4) + 255) / 256, 256, 0, stream>>>(nf, (h4_t*)OUT,
                                                          N * DD / 4, flag);

  int gemm_blocks = ((N + 15) / 16 + 3) / 4;
  int agg_blocks = (N + 3) / 4;
  int rpb = (N + 399) / 400;
  float invN = 1.0f / (float)N;
  int total2 = N * 64;
  int pb = (total2 + 255) / 256;

  const void* Bs[3] = {b1, b2, b3};
  const void* Gs[2] = {g1, g2};
  const void* Bes[2] = {be1, be2};
  for (int l = 0; l < 3; ++l) {
    k_gemm<<<gemm_blocks, 256, 0, stream>>>(OUT, Wt + l * 16384, H16, N);
    if (l < 2) {
      k_agg<0><<<agg_blocks, 256, 0, stream>>>(H16, offs, ccol, cw, Bs[l], OUT,
                                               N, E, flag);
      hipMemsetAsync(stats, 0, 1024, stream);
      k_stats<<<400, 256, 0, stream>>>(OUT, gsum, gsumsq, rpb, N);
      k_polybn<<<pb, 256, 0, stream>>>(OUT, gsum, gsumsq, Gs[l], Bes[l],
                                       coeffs, l * cstride, total2, invN, flag);
    } else {
      k_agg<1><<<agg_blocks, 256, 0, stream>>>(H16, offs, ccol, cw, Bs[l], d_out,
                                               N, E, flag);
    }
  }
}

// Round 8
// 687.012 us; speedup vs baseline: 2.3385x; 1.2273x over previous
//
#include <hip/hip_runtime.h>
#include <hip/hip_bf16.h>

#define DD 128

typedef _Float16 h8_t __attribute__((ext_vector_type(8)));
typedef _Float16 h4_t __attribute__((ext_vector_type(4)));
typedef unsigned short us8_t __attribute__((ext_vector_type(8)));
typedef float f4_t __attribute__((ext_vector_type(4)));

__device__ inline float bf2f(unsigned short u) {
  union { unsigned int i; float f; } v;
  v.i = ((unsigned int)u) << 16;
  return v.f;
}

__device__ inline float sat(float v) {
  return fminf(fmaxf(v, -60000.f), 60000.f);
}

// dtype-adaptive scalar load: mode 1 = float32 array, mode 0 = bf16 array
__device__ inline float ldf(const void* p, int i, int f32m) {
  return f32m ? ((const float*)p)[i] : bf2f(((const unsigned short*)p)[i]);
}

// flag=1 -> f32 inputs
__global__ __launch_bounds__(256) void k_detect(const unsigned int* __restrict__ nf,
                                                int* __restrict__ flag) {
  __shared__ int cnt;
  if (threadIdx.x == 0) cnt = 0;
  __syncthreads();
  int bad = 0;
#pragma unroll
  for (int k = 0; k < 8; ++k) {
    unsigned int w = nf[threadIdx.x * 8 + k];
#pragma unroll
    for (int h = 0; h < 2; ++h) {
      unsigned short us = (h == 0) ? (unsigned short)(w & 0xFFFF)
                                   : (unsigned short)(w >> 16);
      float v = bf2f(us);
      float av = fabsf(v);
      if (!(av <= 1e5f) || (av != 0.f && av < 1e-30f)) bad++;
    }
  }
  atomicAdd(&cnt, bad);
  __syncthreads();
  if (threadIdx.x == 0) *flag = (cnt > 200) ? 1 : 0;
}

// ---------------- CSR build ----------------

__global__ __launch_bounds__(256) void k_hist(const int* __restrict__ row,
                                              int* __restrict__ deg, int E, int N) {
  int i = blockIdx.x * 256 + threadIdx.x;
  if (i < E) {
    int r = row[i];
    if ((unsigned)r < (unsigned)N) atomicAdd(&deg[r], 1);
  }
}

__global__ __launch_bounds__(256) void k_scan1(const int* __restrict__ deg,
                                               int* __restrict__ bsum, int n) {
  int i0 = blockIdx.x * 1024 + threadIdx.x * 4;
  int s = 0;
#pragma unroll
  for (int k = 0; k < 4; ++k) {
    int i = i0 + k;
    if (i < n) s += deg[i];
  }
#pragma unroll
  for (int d = 1; d < 64; d <<= 1) s += __shfl_xor(s, d, 64);
  __shared__ int ws[4];
  int lane = threadIdx.x & 63, w = threadIdx.x >> 6;
  if (lane == 0) ws[w] = s;
  __syncthreads();
  if (threadIdx.x == 0) bsum[blockIdx.x] = ws[0] + ws[1] + ws[2] + ws[3];
}

__global__ __launch_bounds__(1024) void k_scan2(int* __restrict__ bsum,
                                                int* __restrict__ offs,
                                                int nb, int n) {
  __shared__ int sh[1024];
  int tid = threadIdx.x;
  sh[tid] = (tid < nb) ? bsum[tid] : 0;
  __syncthreads();
  if (tid == 0) {
    int run = 0;
    for (int i = 0; i < nb; ++i) {
      int t = sh[i];
      sh[i] = run;
      run += t;
    }
    offs[n] = run;
  }
  __syncthreads();
  if (tid < nb) bsum[tid] = sh[tid];
}

__global__ __launch_bounds__(256) void k_scan3(const int* __restrict__ deg,
                                               const int* __restrict__ bsum,
                                               int* __restrict__ offs,
                                               int* __restrict__ cursor, int n) {
  int tid = threadIdx.x, lane = tid & 63, w = tid >> 6;
  int i0 = blockIdx.x * 1024 + tid * 4;
  int v0 = 0, v1 = 0, v2 = 0, v3 = 0;
  if (i0 + 3 < n) {
    v0 = deg[i0]; v1 = deg[i0 + 1]; v2 = deg[i0 + 2]; v3 = deg[i0 + 3];
  } else {
    if (i0 < n) v0 = deg[i0];
    if (i0 + 1 < n) v1 = deg[i0 + 1];
    if (i0 + 2 < n) v2 = deg[i0 + 2];
  }
  int s = v0 + v1 + v2 + v3;
  int sc = s;
#pragma unroll
  for (int d = 1; d < 64; d <<= 1) {
    int t = __shfl_up(sc, d, 64);
    if (lane >= d) sc += t;
  }
  __shared__ int ws[4];
  if (lane == 63) ws[w] = sc;
  __syncthreads();
  int wbase = 0;
  for (int x = 0; x < w; ++x) wbase += ws[x];
  int run = bsum[blockIdx.x] + wbase + (sc - s);
  if (i0 < n)     { offs[i0] = run;     cursor[i0] = run;     run += v0; }
  if (i0 + 1 < n) { offs[i0 + 1] = run; cursor[i0 + 1] = run; run += v1; }
  if (i0 + 2 < n) { offs[i0 + 2] = run; cursor[i0 + 2] = run; run += v2; }
  if (i0 + 3 < n) { offs[i0 + 3] = run; cursor[i0 + 3] = run; }
}

// packed edge record: {col, weight as f32 bits} — ONE 8B store per edge
__global__ __launch_bounds__(256) void k_fill(const int* __restrict__ row,
                                              const int* __restrict__ col,
                                              const void* __restrict__ ew,
                                              int* __restrict__ cursor,
                                              int2* __restrict__ rec, int E, int N,
                                              const int* __restrict__ flag) {
  int f32m = *flag;
  int i = blockIdx.x * 256 + threadIdx.x;
  if (i >= E) return;
  int r = row[i];
  if ((unsigned)r >= (unsigned)N) return;
  int p = atomicAdd(&cursor[r], 1);
  if ((unsigned)p >= (unsigned)E) return;
  int c = col[i];
  if ((unsigned)c >= (unsigned)N) c = 0;
  rec[p] = make_int2(c, __float_as_int(ldf(ew, i, f32m)));
}

// ---------------- weight swizzle ----------------
// Wt[l][((t*4+kk)*64+lane)*8+j] = W_l[kk*32 + (lane>>4)*8 + j][t*16 + (lane&15)]
__global__ __launch_bounds__(256) void k_cvt_w(const void* __restrict__ W1,
                                               const void* __restrict__ W2,
                                               const void* __restrict__ W3,
                                               _Float16* __restrict__ Wt,
                                               const int* __restrict__ flag) {
  int f32m = *flag;
  int i = blockIdx.x * 256 + threadIdx.x;
  if (i >= 3 * 16384) return;
  int l = i >> 14, o = i & 16383;
  int j = o & 7, lane = (o >> 3) & 63, kkt = o >> 9;
  int kk = kkt & 3, t = kkt >> 2;
  int k = kk * 32 + (lane >> 4) * 8 + j;
  int n = t * 16 + (lane & 15);
  const void* W = (l == 0) ? W1 : (l == 1 ? W2 : W3);
  Wt[i] = (_Float16)ldf(W, k * 128 + n, f32m);
}

// ---------------- BN prep: per-column scale/shift + decoded poly coeffs ------
// bn[0..127]=sc, bn[128..255]=sh, bn[256..260]=p0..p4

__global__ __launch_bounds__(128) void k_bnprep(const float* __restrict__ gsum,
                                                const float* __restrict__ gsumsq,
                                                const void* __restrict__ gamma,
                                                const void* __restrict__ beta,
                                                const void* __restrict__ coeffs,
                                                int coff, float invN,
                                                float* __restrict__ bn,
                                                const int* __restrict__ flag) {
  int f32m = *flag;
  int c = threadIdx.x;
  float mn = gsum[c] * invN;
  float var = fmaf(-mn, mn, gsumsq[c] * invN);
  var = fmaxf(var, 0.0f);
  float inv = rsqrtf(var + 1e-5f);
  float g = ldf(gamma, c, f32m);
  float scv = g * inv;
  bn[c] = scv;
  bn[128 + c] = ldf(beta, c, f32m) - mn * scv;
  if (c < 5) bn[256 + c] = ldf(coeffs, coff + c, f32m);
}

// ---------------- GEMM (MFMA): H = act(X) @ W ----------------
// MODE 0: X = raw input (f32 or bf16 per flag), no activation (layer 0)
// MODE 1: X = fp16 agg output; apply BN (sc,sh) + 4th-order Horner inline
// A frag: m=lane&15, k=(lane>>4)*8+j.  B pre-swizzled.  C/D: col=m, row=q*4+reg.

template <int MODE>
__global__ __launch_bounds__(256) void k_gemm(const void* __restrict__ Xraw,
                                              const _Float16* __restrict__ Wt,
                                              _Float16* __restrict__ H, int nrows,
                                              const float* __restrict__ bn,
                                              const int* __restrict__ flag) {
  int gw = (blockIdx.x * 256 + threadIdx.x) >> 6;
  int lane = threadIdx.x & 63;
  int r0 = gw << 4;
  if (r0 >= nrows) return;
  int m = lane & 15, q = lane >> 4;
  int rr = r0 + m;
  if (rr >= nrows) rr = nrows - 1;
  h8_t a[4];
  if (MODE == 0) {
    int f32m = *flag;
    if (f32m) {
      const float* X = (const float*)Xraw + (size_t)rr * DD + q * 8;
#pragma unroll
      for (int kk = 0; kk < 4; ++kk) {
        float4 u0 = *(const float4*)(X + kk * 32);
        float4 u1 = *(const float4*)(X + kk * 32 + 4);
        a[kk] = h8_t{(_Float16)u0.x, (_Float16)u0.y, (_Float16)u0.z, (_Float16)u0.w,
                     (_Float16)u1.x, (_Float16)u1.y, (_Float16)u1.z, (_Float16)u1.w};
      }
    } else {
      const unsigned short* X = (const unsigned short*)Xraw + (size_t)rr * DD + q * 8;
#pragma unroll
      for (int kk = 0; kk < 4; ++kk) {
        us8_t u = *(const us8_t*)(X + kk * 32);
        h8_t o;
#pragma unroll
        for (int j = 0; j < 8; ++j) o[j] = (_Float16)bf2f(u[j]);
        a[kk] = o;
      }
    }
  } else {
    const _Float16* X = (const _Float16*)Xraw + (size_t)rr * DD + q * 8;
    const float* scp = bn;
    const float* shp = bn + 128;
    float p0 = bn[256], p1 = bn[257], p2 = bn[258], p3 = bn[259], p4 = bn[260];
#pragma unroll
    for (int kk = 0; kk < 4; ++kk) {
      h8_t x = *(const h8_t*)(X + kk * 32);
      int c0 = kk * 32 + q * 8;
      float scv[8], shv[8];
      *(float4*)scv = *(const float4*)(scp + c0);
      *(float4*)(scv + 4) = *(const float4*)(scp + c0 + 4);
      *(float4*)shv = *(const float4*)(shp + c0);
      *(float4*)(shv + 4) = *(const float4*)(shp + c0 + 4);
      h8_t o;
#pragma unroll
      for (int j = 0; j < 8; ++j) {
        float xn = fmaf((float)x[j], scv[j], shv[j]);
        xn = fminf(fmaxf(xn, -100.f), 100.f);
        float h = p4;
        h = fmaf(h, xn, p3);
        h = fmaf(h, xn, p2);
        h = fmaf(h, xn, p1);
        h = fmaf(h, xn, p0);
        o[j] = (_Float16)h;
      }
      a[kk] = o;
    }
  }
  f4_t acc[8] = {};
#pragma unroll
  for (int kk = 0; kk < 4; ++kk) {
#pragma unroll
    for (int t = 0; t < 8; ++t) {
      h8_t b = *(const h8_t*)(Wt + (((t * 4 + kk) * 64 + lane) << 3));
      acc[t] = __builtin_amdgcn_mfma_f32_16x16x32_f16(a[kk], b, acc[t], 0, 0, 0);
    }
  }
#pragma unroll
  for (int t = 0; t < 8; ++t) {
#pragma unroll
    for (int r = 0; r < 4; ++r) {
      int orow = r0 + q * 4 + r;
      if (orow < nrows)
        H[(size_t)orow * DD + t * 16 + m] = (_Float16)sat(acc[t][r]);
    }
  }
}

// ---------------- CSR aggregation: 2 edges/iter, half-wave each ----------------
// FINAL=0: fp16 out.  FINAL=1: float32 out (d_out's dtype).

template <int FINAL>
__global__ __launch_bounds__(256) void k_agg(const _Float16* __restrict__ h,
                                             const int* __restrict__ offs,
                                             const int2* __restrict__ rec,
                                             const void* __restrict__ bias,
                                             void* __restrict__ outp, int n, int E,
                                             const int* __restrict__ flag) {
  int f32m = *flag;
  int node = (blockIdx.x << 2) + (threadIdx.x >> 6);
  if (node >= n) return;
  int lane = threadIdx.x & 63;
  int sub = lane >> 5;   // which of 2 concurrent edges
  int fl = lane & 31;    // feature group (4 features)
  int beg = offs[node], end = offs[node + 1];
  if (beg < 0) beg = 0;
  if (end > E) end = E;
  const uint2* h64 = (const uint2*)h;
  f4_t acc = {};
  for (int base = beg; base < end; base += 64) {
    int mm = end - base;
    if (mm > 64) mm = 64;
    int c = 0, wb = 0;
    if (lane < mm) {
      int2 r = rec[base + lane];
      c = r.x;
      wb = r.y;
    }
#pragma unroll 2
    for (int j = 0; j < mm; j += 2) {
      int idx = j + sub;  // <= 63 always (mm<=64, j even)
      int cc = __shfl(c, idx);
      float ww = __int_as_float(__shfl(wb, idx));  // 0.0 when idx>=mm
      if ((unsigned)cc >= (unsigned)n) cc = 0;
      uint2 pk = h64[(size_t)cc * 32 + fl];
      union { uint2 u; h4_t f; } cv;
      cv.u = pk;
      acc[0] = fmaf((float)cv.f[0], ww, acc[0]);
      acc[1] = fmaf((float)cv.f[1], ww, acc[1]);
      acc[2] = fmaf((float)cv.f[2], ww, acc[2]);
      acc[3] = fmaf((float)cv.f[3], ww, acc[3]);
    }
  }
#pragma unroll
  for (int k = 0; k < 4; ++k) acc[k] += __shfl_xor(acc[k], 32);
  if (sub == 0) {
    int c0 = fl << 2;
    float o0 = sat(acc[0] + ldf(bias, c0, f32m));
    float o1 = sat(acc[1] + ldf(bias, c0 + 1, f32m));
    float o2 = sat(acc[2] + ldf(bias, c0 + 2, f32m));
    float o3 = sat(acc[3] + ldf(bias, c0 + 3, f32m));
    if (FINAL) {
      float4 v = make_float4(o0, o1, o2, o3);
      ((float4*)outp)[(size_t)node * 32 + fl] = v;
    } else {
      h4_t v = {(_Float16)o0, (_Float16)o1, (_Float16)o2, (_Float16)o3};
      ((h4_t*)outp)[(size_t)node * 32 + fl] = v;
    }
  }
}

// ---------------- BN stats ----------------

__global__ __launch_bounds__(256) void k_stats(const _Float16* __restrict__ x,
                                               float* __restrict__ gsum,
                                               float* __restrict__ gsumsq,
                                               int rpb, int n) {
  int c = threadIdx.x & 127, hh = threadIdx.x >> 7;
  int r0 = blockIdx.x * rpb;
  int r1 = r0 + rpb;
  if (r1 > n) r1 = n;
  float s = 0.f, s2 = 0.f;
  for (int r = r0 + hh; r < r1; r += 2) {
    float v = (float)x[(size_t)r * DD + c];
    s += v;
    s2 = fmaf(v, v, s2);
  }
  __shared__ float ls[256], ls2[256];
  ls[threadIdx.x] = s;
  ls2[threadIdx.x] = s2;
  __syncthreads();
  if (threadIdx.x < 128) {
    atomicAdd(&gsum[c], ls[c] + ls[c + 128]);
    atomicAdd(&gsumsq[c], ls2[c] + ls2[c + 128]);
  }
}

// ---------------- launch ----------------

extern "C" void kernel_launch(void* const* d_in, const int* in_sizes, int n_in,
                              void* d_out, int out_size, void* d_ws, size_t ws_size,
                              hipStream_t stream) {
  const void* nf = d_in[0];
  const int* row = (const int*)d_in[1];
  const int* col = (const int*)d_in[2];
  const void* ew = d_in[3];
  const void* W1 = d_in[4];
  const void* b1 = d_in[5];
  const void* W2 = d_in[6];
  const void* b2 = d_in[7];
  const void* W3 = d_in[8];
  const void* b3 = d_in[9];
  const void* g1 = d_in[10];
  const void* be1 = d_in[11];
  const void* g2 = d_in[12];
  const void* be2 = d_in[13];
  const void* coeffs = d_in[14];

  const int N = in_sizes[0] / DD;
  const int E = in_sizes[1];
  const int cstride = in_sizes[14] / 2;

  // ws ≈ 40MB (R1 evidence: ws_size ≥ 66MB)
  char* p = (char*)d_ws;
  auto alloc = [&](size_t bytes) {
    char* r = p;
    p += (bytes + 255) & ~(size_t)255;
    return r;
  };
  int* flag = (int*)alloc(256);
  float* stats = (float*)alloc(2048);  // gsum 128 | gsumsq 128 | bn: sc128 sh128 p5
  float* gsum = stats;
  float* gsumsq = stats + 128;
  float* bn = stats + 256;
  int* bsum = (int*)alloc(4096);
  _Float16* Wt = (_Float16*)alloc(3 * 16384 * 2);
  _Float16* H16 = (_Float16*)alloc((size_t)N * DD * 2);
  int* deg = (int*)alloc((size_t)N * 4);
  int* offs = (int*)alloc((size_t)(N + 1) * 4);
  int* cursor = (int*)alloc((size_t)N * 4);
  int2* rec = (int2*)alloc((size_t)E * 8);

  _Float16* OUT = (_Float16*)d_out;  // fp16 agg scratch; k_agg<1> rewrites as f32

  k_detect<<<1, 256, 0, stream>>>((const unsigned int*)nf, flag);

  int eb = (E + 255) / 256;
  hipMemsetAsync(deg, 0, (size_t)N * 4, stream);
  k_hist<<<eb, 256, 0, stream>>>(row, deg, E, N);
  int nb = (N + 1023) / 1024;
  k_scan1<<<nb, 256, 0, stream>>>(deg, bsum, N);
  k_scan2<<<1, 1024, 0, stream>>>(bsum, offs, nb, N);
  k_scan3<<<nb, 256, 0, stream>>>(deg, bsum, offs, cursor, N);
  k_fill<<<eb, 256, 0, stream>>>(row, col, ew, cursor, rec, E, N, flag);

  k_cvt_w<<<192, 256, 0, stream>>>(W1, W2, W3, Wt, flag);

  int gemm_blocks = ((N + 15) / 16 + 3) / 4;
  int agg_blocks = (N + 3) / 4;
  int rpb = (N + 399) / 400;
  float invN = 1.0f / (float)N;

  const void* Bs[3] = {b1, b2, b3};
  const void* Gs[2] = {g1, g2};
  const void* Bes[2] = {be1, be2};

  // layer 0: raw input -> gemm -> agg -> stats -> bnprep
  k_gemm<0><<<gemm_blocks, 256, 0, stream>>>(nf, Wt, H16, N, bn, flag);
  k_agg<0><<<agg_blocks, 256, 0, stream>>>(H16, offs, rec, Bs[0], OUT, N, E, flag);
  hipMemsetAsync(stats, 0, 1024, stream);
  k_stats<<<400, 256, 0, stream>>>(OUT, gsum, gsumsq, rpb, N);
  k_bnprep<<<1, 128, 0, stream>>>(gsum, gsumsq, Gs[0], Bes[0], coeffs, 0, invN, bn, flag);

  // layer 1: fused BN+poly gemm -> agg -> stats -> bnprep
  k_gemm<1><<<gemm_blocks, 256, 0, stream>>>(OUT, Wt + 16384, H16, N, bn, flag);
  k_agg<0><<<agg_blocks, 256, 0, stream>>>(H16, offs, rec, Bs[1], OUT, N, E, flag);
  hipMemsetAsync(stats, 0, 1024, stream);
  k_stats<<<400, 256, 0, stream>>>(OUT, gsum, gsumsq, rpb, N);
  k_bnprep<<<1, 128, 0, stream>>>(gsum, gsumsq, Gs[1], Bes[1], coeffs, cstride, invN, bn, flag);

  // layer 2: fused BN+poly gemm -> agg (float32 out)
  k_gemm<1><<<gemm_blocks, 256, 0, stream>>>(OUT, Wt + 2 * 16384, H16, N, bn, flag);
  k_agg<1><<<agg_blocks, 256, 0, stream>>>(H16, offs, rec, Bs[2], d_out, N, E, flag);
}